// Round 1
// baseline (658.377 us; speedup 1.0000x reference)
//
#include <hip/hip_runtime.h>
#include <hip/hip_bf16.h>
#include <math.h>

#define N_NODES 50000
#define N_EDGES 800000
#define DIM 256
#define MPAD 50048   /* 782*64 */
#define LN_EPS 1e-5f

typedef short bf16x8 __attribute__((ext_vector_type(8)));
typedef float f32x4 __attribute__((ext_vector_type(4)));
typedef unsigned short u16;
typedef u16 u16x8 __attribute__((ext_vector_type(8)));

__device__ __forceinline__ u16 f2bf(float f) {
    union { float f; unsigned u; } v; v.f = f;
    unsigned r = (v.u + 0x7FFFu + ((v.u >> 16) & 1u)) >> 16;
    return (u16)r;
}
__device__ __forceinline__ float bf2f(u16 h) {
    union { unsigned u; float f; } v; v.u = ((unsigned)h) << 16;
    return v.f;
}

// ---------------- CSR build ----------------
__global__ void count_kernel(const int* __restrict__ dst, int* __restrict__ counts) {
    int e = blockIdx.x * 256 + threadIdx.x;
    if (e < N_EDGES) atomicAdd(&counts[dst[e]], 1);
}

__global__ void scan_kernel(const int* __restrict__ counts, int* __restrict__ offsets,
                            int* __restrict__ cursor) {
    __shared__ int lsum[1024];
    int tid = threadIdx.x;
    const int PER = (N_NODES + 1023) / 1024;  // 49
    int start = tid * PER;
    int end = min(start + PER, N_NODES);
    int s = 0;
    for (int i = start; i < end; ++i) s += counts[i];
    lsum[tid] = s;
    __syncthreads();
    for (int off = 1; off < 1024; off <<= 1) {
        int v = (tid >= off) ? lsum[tid - off] : 0;
        __syncthreads();
        lsum[tid] += v;
        __syncthreads();
    }
    int run = lsum[tid] - s;  // exclusive prefix
    for (int i = start; i < end; ++i) {
        offsets[i] = run; cursor[i] = run;
        run += counts[i];
    }
    if (tid == 1023) offsets[N_NODES] = lsum[1023];
}

__global__ void scatter_kernel(const int* __restrict__ src, const int* __restrict__ dst,
                               const float* __restrict__ w, int* __restrict__ cursor,
                               int* __restrict__ sperm, float* __restrict__ wperm) {
    int e = blockIdx.x * 256 + threadIdx.x;
    if (e < N_EDGES) {
        int d = dst[e];
        int p = atomicAdd(&cursor[d], 1);
        sperm[p] = src[e];
        wperm[p] = w[e];
    }
}

// ---------------- weight transpose + bf16 convert ----------------
// WT[m][n][k] = bf16(W_m[k][n]);  m in {0:W1, 1:W2, 2:Wp}
__global__ void convw_kernel(const float* __restrict__ W1, const float* __restrict__ W2,
                             const float* __restrict__ Wp, u16* __restrict__ WT) {
    int idx = blockIdx.x * 256 + threadIdx.x;  // 0..196607
    int m = idx >> 16;
    int r = idx & 65535;
    int n = r >> 8, k = r & 255;
    const float* W = (m == 0) ? W1 : (m == 1) ? W2 : Wp;
    WT[idx] = f2bf(W[k * 256 + n]);
}

// ---------------- SPMM: y[i] = x[i] + sum_{e: dst=i} w_e * x[src_e] (bf16 out) ----
template <bool IN_BF16>
__global__ void spmm_kernel(const void* __restrict__ xin_, const int* __restrict__ offs,
                            const int* __restrict__ sperm, const float* __restrict__ wperm,
                            u16* __restrict__ y) {
    int wave = threadIdx.x >> 6;
    int lane = threadIdx.x & 63;
    int node = blockIdx.x * 4 + wave;
    if (node >= N_NODES) return;

    float acc0, acc1, acc2, acc3;
    if (IN_BF16) {
        const u16* x = (const u16*)xin_;
        ushort4 v = ((const ushort4*)(x + (size_t)node * 256))[lane];
        acc0 = bf2f(v.x); acc1 = bf2f(v.y); acc2 = bf2f(v.z); acc3 = bf2f(v.w);
    } else {
        const float* x = (const float*)xin_;
        float4 v = ((const float4*)(x + (size_t)node * 256))[lane];
        acc0 = v.x; acc1 = v.y; acc2 = v.z; acc3 = v.w;
    }
    int p1 = offs[node + 1];
    for (int p = offs[node]; p < p1; ++p) {
        int s = sperm[p];
        float w = wperm[p];
        if (IN_BF16) {
            const u16* x = (const u16*)xin_;
            ushort4 v = ((const ushort4*)(x + (size_t)s * 256))[lane];
            acc0 += w * bf2f(v.x); acc1 += w * bf2f(v.y);
            acc2 += w * bf2f(v.z); acc3 += w * bf2f(v.w);
        } else {
            const float* x = (const float*)xin_;
            float4 v = ((const float4*)(x + (size_t)s * 256))[lane];
            acc0 += w * v.x; acc1 += w * v.y; acc2 += w * v.z; acc3 += w * v.w;
        }
    }
    ushort4 o;
    o.x = f2bf(acc0); o.y = f2bf(acc1); o.z = f2bf(acc2); o.w = f2bf(acc3);
    ((ushort4*)(y + (size_t)node * 256))[lane] = o;
}

// ---------------- GEMM 64x256 tile, bf16 MFMA, fused bias(+LN+gelu) ----------------
// MODE 0: xb_out[row][c] = bf16(gelu(LN(A@B + bias)))   (rows up to MPAD, no guard)
// MODE 1: f_out[row][c]  = A@B + bias                   (guard row < N_NODES)
#define BK 32
#define LDA 40  // padded LDS leading dim (bf16 elems): 20 banks -> <=2-way conflict

template <int MODE>
__global__ __launch_bounds__(256) void gemm_kernel(
        const u16* __restrict__ A, const u16* __restrict__ BT,
        const float* __restrict__ bias, const float* __restrict__ g,
        const float* __restrict__ be, u16* __restrict__ xb_out,
        float* __restrict__ f_out) {
    __shared__ u16 a_lds[64 * LDA];    // 5 KB
    __shared__ u16 b_lds[256 * LDA];   // 20 KB
    int tid = threadIdx.x;
    int wave = tid >> 6, lane = tid & 63;
    int quad = lane >> 4, l15 = lane & 15;
    int row0 = blockIdx.x * 64;

    f32x4 acc[16];
    for (int t = 0; t < 16; ++t) acc[t] = {0.f, 0.f, 0.f, 0.f};

    int ar = tid >> 2;             // A stage: row 0..63
    int ac = (tid & 3) * 8;        // col chunk 0/8/16/24
    const u16* gaBase = A + (size_t)(row0 + ar) * 256 + ac;
    const u16* gbBase = BT + (size_t)tid * 256;

    for (int kb = 0; kb < 256; kb += BK) {
        // stage A tile (64x32 bf16)
        u16x8 av = *(const u16x8*)(gaBase + kb);
        *(u16x8*)&a_lds[ar * LDA + ac] = av;
        // stage B tile (256 n-rows x 32 k)
        const u16* gb = gbBase + kb;
        u16x8 b0 = *(const u16x8*)(gb);
        u16x8 b1 = *(const u16x8*)(gb + 8);
        u16x8 b2 = *(const u16x8*)(gb + 16);
        u16x8 b3 = *(const u16x8*)(gb + 24);
        *(u16x8*)&b_lds[tid * LDA + 0]  = b0;
        *(u16x8*)&b_lds[tid * LDA + 8]  = b1;
        *(u16x8*)&b_lds[tid * LDA + 16] = b2;
        *(u16x8*)&b_lds[tid * LDA + 24] = b3;
        __syncthreads();

        bf16x8 afrag = *(const bf16x8*)&a_lds[(wave * 16 + l15) * LDA + quad * 8];
#pragma unroll
        for (int t = 0; t < 16; ++t) {
            bf16x8 bfrag = *(const bf16x8*)&b_lds[(t * 16 + l15) * LDA + quad * 8];
            acc[t] = __builtin_amdgcn_mfma_f32_16x16x32_bf16(afrag, bfrag, acc[t], 0, 0, 0);
        }
        __syncthreads();
    }

    if (MODE == 0) {
#pragma unroll
        for (int t = 0; t < 16; ++t) {
            float bv = bias[t * 16 + l15];
#pragma unroll
            for (int i = 0; i < 4; ++i) acc[t][i] += bv;
        }
#pragma unroll
        for (int i = 0; i < 4; ++i) {
            float s = 0.f, q = 0.f;
#pragma unroll
            for (int t = 0; t < 16; ++t) { float v = acc[t][i]; s += v; q += v * v; }
            for (int off = 1; off < 16; off <<= 1) {
                s += __shfl_xor(s, off);
                q += __shfl_xor(q, off);
            }
            float mu = s * (1.0f / 256.0f);
            float var = q * (1.0f / 256.0f) - mu * mu;
            float rs = rsqrtf(var + LN_EPS);
            int row = row0 + wave * 16 + quad * 4 + i;
#pragma unroll
            for (int t = 0; t < 16; ++t) {
                int c = t * 16 + l15;
                float v = (acc[t][i] - mu) * rs * g[c] + be[c];
                float ge = 0.5f * v * (1.0f + erff(v * 0.70710678118f));
                xb_out[(size_t)row * 256 + c] = f2bf(ge);
            }
        }
    } else {
#pragma unroll
        for (int i = 0; i < 4; ++i) {
            int row = row0 + wave * 16 + quad * 4 + i;
            if (row < N_NODES) {
#pragma unroll
                for (int t = 0; t < 16; ++t) {
                    int c = t * 16 + l15;
                    f_out[(size_t)row * 256 + c] = acc[t][i] + bias[c];
                }
            }
        }
    }
}

extern "C" void kernel_launch(void* const* d_in, const int* in_sizes, int n_in,
                              void* d_out, int out_size, void* d_ws, size_t ws_size,
                              hipStream_t stream) {
    const float* nodef = (const float*)d_in[0];
    const int*   src   = (const int*)d_in[1];
    const int*   dst   = (const int*)d_in[2];
    const float* ew    = (const float*)d_in[3];
    const float* W1 = (const float*)d_in[4];
    const float* b1 = (const float*)d_in[5];
    const float* g1 = (const float*)d_in[6];
    const float* be1 = (const float*)d_in[7];
    const float* W2 = (const float*)d_in[8];
    const float* b2 = (const float*)d_in[9];
    const float* g2 = (const float*)d_in[10];
    const float* be2 = (const float*)d_in[11];
    const float* Wp = (const float*)d_in[12];
    const float* bp = (const float*)d_in[13];
    float* out = (float*)d_out;

    char* ws = (char*)d_ws;
    size_t off = 0;
    auto alloc = [&](size_t bytes) -> void* {
        void* p = ws + off;
        off += (bytes + 255) & ~(size_t)255;
        return p;
    };
    u16*   ybuf    = (u16*)alloc((size_t)MPAD * 256 * 2);
    u16*   xbuf    = (u16*)alloc((size_t)MPAD * 256 * 2);
    u16*   WT      = (u16*)alloc((size_t)3 * 65536 * 2);
    int*   counts  = (int*)alloc((size_t)N_NODES * 4);
    int*   offsets = (int*)alloc((size_t)(N_NODES + 1) * 4);
    int*   cursor  = (int*)alloc((size_t)N_NODES * 4);
    int*   sperm   = (int*)alloc((size_t)N_EDGES * 4);
    float* wperm   = (float*)alloc((size_t)N_EDGES * 4);

    hipMemsetAsync(counts, 0, (size_t)N_NODES * 4, stream);
    count_kernel<<<(N_EDGES + 255) / 256, 256, 0, stream>>>(dst, counts);
    scan_kernel<<<1, 1024, 0, stream>>>(counts, offsets, cursor);
    scatter_kernel<<<(N_EDGES + 255) / 256, 256, 0, stream>>>(src, dst, ew, cursor, sperm, wperm);
    convw_kernel<<<768, 256, 0, stream>>>(W1, W2, Wp, WT);

    const int GB = MPAD / 64;  // 782 gemm blocks
    // layer 1
    spmm_kernel<false><<<(N_NODES + 3) / 4, 256, 0, stream>>>(nodef, offsets, sperm, wperm, ybuf);
    gemm_kernel<0><<<GB, 256, 0, stream>>>(ybuf, WT, b1, g1, be1, xbuf, nullptr);
    // layer 2
    spmm_kernel<true><<<(N_NODES + 3) / 4, 256, 0, stream>>>(xbuf, offsets, sperm, wperm, ybuf);
    gemm_kernel<0><<<GB, 256, 0, stream>>>(ybuf, WT + 65536, b2, g2, be2, xbuf, nullptr);
    // projection
    gemm_kernel<1><<<GB, 256, 0, stream>>>(xbuf, WT + 2 * 65536, bp, nullptr, nullptr, nullptr, out);
}

// Round 2
// 593.058 us; speedup vs baseline: 1.1101x; 1.1101x over previous
//
#include <hip/hip_runtime.h>
#include <hip/hip_bf16.h>
#include <math.h>

#define N_NODES 50000
#define N_EDGES 800000
#define DIM 256
#define MPAD 50048   /* 391*128 */
#define LN_EPS 1e-5f

typedef short bf16x8 __attribute__((ext_vector_type(8)));
typedef float f32x4 __attribute__((ext_vector_type(4)));
typedef unsigned short u16;
typedef u16 u16x8 __attribute__((ext_vector_type(8)));

__device__ __forceinline__ u16 f2bf(float f) {
    union { float f; unsigned u; } v; v.f = f;
    unsigned r = (v.u + 0x7FFFu + ((v.u >> 16) & 1u)) >> 16;
    return (u16)r;
}
__device__ __forceinline__ float bf2f(u16 h) {
    union { unsigned u; float f; } v; v.u = ((unsigned)h) << 16;
    return v.f;
}

// ---------------- CSR build ----------------
__global__ void count_kernel(const int* __restrict__ dst, int* __restrict__ counts) {
    int e = blockIdx.x * 256 + threadIdx.x;
    if (e < N_EDGES) atomicAdd(&counts[dst[e]], 1);
}

__global__ void scan_kernel(const int* __restrict__ counts, int* __restrict__ offsets,
                            int* __restrict__ cursor) {
    __shared__ int lsum[1024];
    int tid = threadIdx.x;
    const int PER = (N_NODES + 1023) / 1024;  // 49
    int start = tid * PER;
    int end = min(start + PER, N_NODES);
    int s = 0;
    for (int i = start; i < end; ++i) s += counts[i];
    lsum[tid] = s;
    __syncthreads();
    for (int off = 1; off < 1024; off <<= 1) {
        int v = (tid >= off) ? lsum[tid - off] : 0;
        __syncthreads();
        lsum[tid] += v;
        __syncthreads();
    }
    int run = lsum[tid] - s;  // exclusive prefix
    for (int i = start; i < end; ++i) {
        offsets[i] = run; cursor[i] = run;
        run += counts[i];
    }
    if (tid == 1023) offsets[N_NODES] = lsum[1023];
}

__global__ void scatter_kernel(const int* __restrict__ src, const int* __restrict__ dst,
                               const float* __restrict__ w, int* __restrict__ cursor,
                               int* __restrict__ sperm, float* __restrict__ wperm) {
    int e = blockIdx.x * 256 + threadIdx.x;
    if (e < N_EDGES) {
        int d = dst[e];
        int p = atomicAdd(&cursor[d], 1);
        sperm[p] = src[e];
        wperm[p] = w[e];
    }
}

// ---------------- f32 -> bf16 row conversion ----------------
__global__ void conv_kernel(const float* __restrict__ in, u16* __restrict__ out) {
    int i = blockIdx.x * 256 + threadIdx.x;  // covers N_NODES*256/4 elements
    float4 v = ((const float4*)in)[i];
    ushort4 o;
    o.x = f2bf(v.x); o.y = f2bf(v.y); o.z = f2bf(v.z); o.w = f2bf(v.w);
    ((ushort4*)out)[i] = o;
}

// ---------------- weight transpose + bf16 convert ----------------
// WT[m][n][k] = bf16(W_m[k][n]);  m in {0:W1, 1:W2, 2:Wp}
__global__ void convw_kernel(const float* __restrict__ W1, const float* __restrict__ W2,
                             const float* __restrict__ Wp, u16* __restrict__ WT) {
    int idx = blockIdx.x * 256 + threadIdx.x;  // 0..196607
    int m = idx >> 16;
    int r = idx & 65535;
    int n = r >> 8, k = r & 255;
    const float* W = (m == 0) ? W1 : (m == 1) ? W2 : Wp;
    WT[idx] = f2bf(W[k * 256 + n]);
}

// ---------------- SPMM: y[i] = x[i] + sum_{e: dst=i} w_e * x[src_e]  ----
// bf16 in, bf16 out. One wave per node, 4-way unrolled edge loop for MLP.
__global__ __launch_bounds__(256) void spmm_kernel(
        const u16* __restrict__ x, const int* __restrict__ offs,
        const int* __restrict__ sperm, const float* __restrict__ wperm,
        u16* __restrict__ y) {
    int wave = threadIdx.x >> 6;
    int lane = threadIdx.x & 63;
    int node = blockIdx.x * 4 + wave;
    if (node >= N_NODES) return;

    const ushort4* xv = (const ushort4*)x;
    ushort4 v = xv[(size_t)node * 64 + lane];
    float a0 = bf2f(v.x), a1 = bf2f(v.y), a2 = bf2f(v.z), a3 = bf2f(v.w);
    float b0 = 0, b1 = 0, b2 = 0, b3 = 0;
    float c0 = 0, c1 = 0, c2 = 0, c3 = 0;
    float d0 = 0, d1 = 0, d2 = 0, d3 = 0;

    int p = offs[node];
    int p1 = offs[node + 1];
    for (; p + 4 <= p1; p += 4) {
        int s0 = sperm[p], s1 = sperm[p + 1], s2 = sperm[p + 2], s3 = sperm[p + 3];
        float w0 = wperm[p], w1 = wperm[p + 1], w2 = wperm[p + 2], w3 = wperm[p + 3];
        ushort4 v0 = xv[(size_t)s0 * 64 + lane];
        ushort4 v1 = xv[(size_t)s1 * 64 + lane];
        ushort4 v2 = xv[(size_t)s2 * 64 + lane];
        ushort4 v3 = xv[(size_t)s3 * 64 + lane];
        a0 += w0 * bf2f(v0.x); a1 += w0 * bf2f(v0.y); a2 += w0 * bf2f(v0.z); a3 += w0 * bf2f(v0.w);
        b0 += w1 * bf2f(v1.x); b1 += w1 * bf2f(v1.y); b2 += w1 * bf2f(v1.z); b3 += w1 * bf2f(v1.w);
        c0 += w2 * bf2f(v2.x); c1 += w2 * bf2f(v2.y); c2 += w2 * bf2f(v2.z); c3 += w2 * bf2f(v2.w);
        d0 += w3 * bf2f(v3.x); d1 += w3 * bf2f(v3.y); d2 += w3 * bf2f(v3.z); d3 += w3 * bf2f(v3.w);
    }
    for (; p < p1; ++p) {
        int s = sperm[p];
        float w = wperm[p];
        ushort4 vv = xv[(size_t)s * 64 + lane];
        a0 += w * bf2f(vv.x); a1 += w * bf2f(vv.y); a2 += w * bf2f(vv.z); a3 += w * bf2f(vv.w);
    }
    a0 += b0 + c0 + d0; a1 += b1 + c1 + d1;
    a2 += b2 + c2 + d2; a3 += b3 + c3 + d3;
    ushort4 o;
    o.x = f2bf(a0); o.y = f2bf(a1); o.z = f2bf(a2); o.w = f2bf(a3);
    ((ushort4*)(y + (size_t)node * 256))[lane] = o;
}

// ---------------- GEMM 128x256 tile, bf16 MFMA, reg-prefetch pipeline ------
// MODE 0: xb_out[row][c] = bf16(gelu(LN(A@B + bias)))   (rows to MPAD, no guard)
// MODE 1: f_out[row][c]  = A@B + bias                   (guard row < N_NODES)
#define LDA 40  // padded LDS leading dim (bf16): word-stride 20 -> conflict-free (measured)

template <int MODE>
__global__ __launch_bounds__(256, 2) void gemm_kernel(
        const u16* __restrict__ A, const u16* __restrict__ BT,
        const float* __restrict__ bias, const float* __restrict__ g,
        const float* __restrict__ be, u16* __restrict__ xb_out,
        float* __restrict__ f_out) {
    __shared__ u16 a_lds[128 * LDA];   // 10 KB
    __shared__ u16 b_lds[256 * LDA];   // 20 KB
    int tid = threadIdx.x;
    int wave = tid >> 6, lane = tid & 63;
    int quad = lane >> 4, l15 = lane & 15;
    int row0 = blockIdx.x * 128;

    f32x4 acc0[16], acc1[16];
#pragma unroll
    for (int t = 0; t < 16; ++t) { acc0[t] = {0.f, 0.f, 0.f, 0.f}; acc1[t] = {0.f, 0.f, 0.f, 0.f}; }

    // A staging map: thread -> row (tid>>1), 16-col half ((tid&1)*16), two u16x8 chunks
    int ar = tid >> 1;
    int ah = (tid & 1) * 16;
    const u16* ga = A + (size_t)(row0 + ar) * 256 + ah;
    const u16* gb = BT + (size_t)tid * 256;

    u16x8 pa0 = *(const u16x8*)(ga);
    u16x8 pa1 = *(const u16x8*)(ga + 8);
    u16x8 pb0 = *(const u16x8*)(gb);
    u16x8 pb1 = *(const u16x8*)(gb + 8);
    u16x8 pb2 = *(const u16x8*)(gb + 16);
    u16x8 pb3 = *(const u16x8*)(gb + 24);

    for (int kb = 0; kb < 8; ++kb) {
        if (kb) __syncthreads();   // prior iter's LDS consumers done
        *(u16x8*)&a_lds[ar * LDA + ah] = pa0;
        *(u16x8*)&a_lds[ar * LDA + ah + 8] = pa1;
        *(u16x8*)&b_lds[tid * LDA + 0]  = pb0;
        *(u16x8*)&b_lds[tid * LDA + 8]  = pb1;
        *(u16x8*)&b_lds[tid * LDA + 16] = pb2;
        *(u16x8*)&b_lds[tid * LDA + 24] = pb3;
        __syncthreads();
        if (kb < 7) {              // prefetch next K-tile while MFMA consumes LDS
            int ko = (kb + 1) * 32;
            pa0 = *(const u16x8*)(ga + ko);
            pa1 = *(const u16x8*)(ga + ko + 8);
            pb0 = *(const u16x8*)(gb + ko);
            pb1 = *(const u16x8*)(gb + ko + 8);
            pb2 = *(const u16x8*)(gb + ko + 16);
            pb3 = *(const u16x8*)(gb + ko + 24);
        }
        bf16x8 af0 = *(const bf16x8*)&a_lds[(wave * 32 + l15) * LDA + quad * 8];
        bf16x8 af1 = *(const bf16x8*)&a_lds[(wave * 32 + 16 + l15) * LDA + quad * 8];
#pragma unroll
        for (int t = 0; t < 16; ++t) {
            bf16x8 bf = *(const bf16x8*)&b_lds[(t * 16 + l15) * LDA + quad * 8];
            acc0[t] = __builtin_amdgcn_mfma_f32_16x16x32_bf16(af0, bf, acc0[t], 0, 0, 0);
            acc1[t] = __builtin_amdgcn_mfma_f32_16x16x32_bf16(af1, bf, acc1[t], 0, 0, 0);
        }
    }

#pragma unroll
    for (int rf = 0; rf < 2; ++rf) {
        f32x4* acc = rf ? acc1 : acc0;
        int rbase = row0 + wave * 32 + rf * 16 + quad * 4;
        if (MODE == 0) {
#pragma unroll
            for (int t = 0; t < 16; ++t) {
                float bv = bias[t * 16 + l15];
#pragma unroll
                for (int i = 0; i < 4; ++i) acc[t][i] += bv;
            }
#pragma unroll
            for (int i = 0; i < 4; ++i) {
                float s = 0.f, q = 0.f;
#pragma unroll
                for (int t = 0; t < 16; ++t) { float v = acc[t][i]; s += v; q += v * v; }
                for (int off = 1; off < 16; off <<= 1) {
                    s += __shfl_xor(s, off);
                    q += __shfl_xor(q, off);
                }
                float mu = s * (1.0f / 256.0f);
                float var = q * (1.0f / 256.0f) - mu * mu;
                float rs = rsqrtf(var + LN_EPS);
                int row = rbase + i;
#pragma unroll
                for (int t = 0; t < 16; ++t) {
                    int c = t * 16 + l15;
                    float v = (acc[t][i] - mu) * rs * g[c] + be[c];
                    float ge = 0.5f * v * (1.0f + erff(v * 0.70710678118f));
                    xb_out[(size_t)row * 256 + c] = f2bf(ge);
                }
            }
        } else {
#pragma unroll
            for (int i = 0; i < 4; ++i) {
                int row = rbase + i;
                if (row < N_NODES) {
#pragma unroll
                    for (int t = 0; t < 16; ++t) {
                        int c = t * 16 + l15;
                        f_out[(size_t)row * 256 + c] = acc[t][i] + bias[c];
                    }
                }
            }
        }
    }
}

extern "C" void kernel_launch(void* const* d_in, const int* in_sizes, int n_in,
                              void* d_out, int out_size, void* d_ws, size_t ws_size,
                              hipStream_t stream) {
    const float* nodef = (const float*)d_in[0];
    const int*   src   = (const int*)d_in[1];
    const int*   dst   = (const int*)d_in[2];
    const float* ew    = (const float*)d_in[3];
    const float* W1 = (const float*)d_in[4];
    const float* b1 = (const float*)d_in[5];
    const float* g1 = (const float*)d_in[6];
    const float* be1 = (const float*)d_in[7];
    const float* W2 = (const float*)d_in[8];
    const float* b2 = (const float*)d_in[9];
    const float* g2 = (const float*)d_in[10];
    const float* be2 = (const float*)d_in[11];
    const float* Wp = (const float*)d_in[12];
    const float* bp = (const float*)d_in[13];
    float* out = (float*)d_out;

    char* ws = (char*)d_ws;
    size_t off = 0;
    auto alloc = [&](size_t bytes) -> void* {
        void* p = ws + off;
        off += (bytes + 255) & ~(size_t)255;
        return p;
    };
    u16*   ybuf    = (u16*)alloc((size_t)MPAD * 256 * 2);
    u16*   xbuf    = (u16*)alloc((size_t)MPAD * 256 * 2);
    u16*   WT      = (u16*)alloc((size_t)3 * 65536 * 2);
    int*   counts  = (int*)alloc((size_t)N_NODES * 4);
    int*   offsets = (int*)alloc((size_t)(N_NODES + 1) * 4);
    int*   cursor  = (int*)alloc((size_t)N_NODES * 4);
    int*   sperm   = (int*)alloc((size_t)N_EDGES * 4);
    float* wperm   = (float*)alloc((size_t)N_EDGES * 4);

    hipMemsetAsync(counts, 0, (size_t)N_NODES * 4, stream);
    count_kernel<<<(N_EDGES + 255) / 256, 256, 0, stream>>>(dst, counts);
    scan_kernel<<<1, 1024, 0, stream>>>(counts, offsets, cursor);
    scatter_kernel<<<(N_EDGES + 255) / 256, 256, 0, stream>>>(src, dst, ew, cursor, sperm, wperm);
    conv_kernel<<<(N_NODES * 256 / 4) / 256, 256, 0, stream>>>(nodef, xbuf);
    convw_kernel<<<768, 256, 0, stream>>>(W1, W2, Wp, WT);

    const int GB = MPAD / 128;  // 391 gemm blocks
    // layer 1  (xbuf holds bf16 node features; gemm1 overwrites it after spmm consumed it)
    spmm_kernel<<<(N_NODES + 3) / 4, 256, 0, stream>>>(xbuf, offsets, sperm, wperm, ybuf);
    gemm_kernel<0><<<GB, 256, 0, stream>>>(ybuf, WT, b1, g1, be1, xbuf, nullptr);
    // layer 2
    spmm_kernel<<<(N_NODES + 3) / 4, 256, 0, stream>>>(xbuf, offsets, sperm, wperm, ybuf);
    gemm_kernel<0><<<GB, 256, 0, stream>>>(ybuf, WT + 65536, b2, g2, be2, xbuf, nullptr);
    // projection
    gemm_kernel<1><<<GB, 256, 0, stream>>>(xbuf, WT + 2 * 65536, bp, nullptr, nullptr, nullptr, out);
}